// Round 5
// baseline (54058.936 us; speedup 1.0000x reference)
//
#include <hip/hip_runtime.h>
#include <stdint.h>

// DiffusionModel: 1000 sequential forward noise+clip steps + 1 reverse step.
// JAX *partitionable* threefry semantics (default since JAX 0.4.36):
//   split(key,n):  child_t = threefry2x32(key, (0, t)); child = (o0, o1)
//   random_bits32: bits[i] = o0 ^ o1 of threefry2x32(key, (0, i))   (XOR-fold)
//   fold_in:       threefry2x32(key, (0, data))
//
// R5 vs R4: erfinv made fully BRANCHLESS (deterministic issue cost).
// R4 measured ~157 VALU slots/element-step vs ~112 mandatory; theory: the
// 4 inlined tail-branch sites/iter (20% wave-divergence each) + exec-mask
// machinery ate ~45 slots. Now: one v_cmp, 9 coefficient cndmasks, one
// shared 8-fma Horner, sqrt always issued (raw, 1 ulp).
// Compile-time foldings (each <=2 ulp/draw vs ref, budget is ~1e-5/draw):
//   - ln2 folded into s-transform: use raw v_log_f32 (log2), never mul by ln2
//     separately for the central path: s_c = fma(-ln2, g, -2.5)
//   - 0.1f*1.41421356f folded into all 18 Giles coefficients: noise = p*x
// Kept ref-identical (NOT folded): u = fma(f,2,lo); v = 1 - RN(u*u) as two
// roundings (fma here would change tail v by up to 50% rel -> absmax blowup).

#define NTOTAL 25165824u
#define EPT    4u
#define NTHREADS (NTOTAL / EPT)   // 6,291,456 threads = 24576 blocks x 256
#define TS     1000

__device__ __forceinline__ uint32_t rotl32(uint32_t x, int r) {
  return __builtin_amdgcn_alignbit(x, x, 32 - r);  // 1x v_alignbit_b32
}

__device__ __forceinline__ void tf2x32(uint32_t k0, uint32_t k1,
                                       uint32_t x0, uint32_t x1,
                                       uint32_t& o0, uint32_t& o1) {
  const uint32_t k2 = k0 ^ k1 ^ 0x1BD11BDAu;
  x0 += k0; x1 += k1;
#define RR(r) { x0 += x1; x1 = rotl32(x1, r); x1 ^= x0; }
  RR(13) RR(15) RR(26) RR(6)
  x0 += k1; x1 += k2 + 1u;
  RR(17) RR(29) RR(16) RR(24)
  x0 += k2; x1 += k0 + 2u;
  RR(13) RR(15) RR(26) RR(6)
  x0 += k0; x1 += k1 + 3u;
  RR(17) RR(29) RR(16) RR(24)
  x0 += k1; x1 += k2 + 4u;
  RR(13) RR(15) RR(26) RR(6)
  x0 += k2; x1 += k0 + 5u;
#undef RR
  o0 = x0; o1 = x1;
}

__device__ __forceinline__ uint32_t tf_bits(uint32_t k0, uint32_t k1, uint32_t i) {
  uint32_t o0, o1;
  tf2x32(k0, k1, 0u, i, o0, o1);
  return o0 ^ o1;
}

// Giles coefficients pre-scaled by K = 0.1f * 1.41421356f (host-folded in
// double, single f32 rounding each — <=1 ulp rel vs ref's two post-muls).
#define KSC (0.1f * 1.41421356f)
__device__ __constant__ const float CC[9] = {  // central, w<5, s = w-2.5
  (float)((double)KSC * 2.81022636e-08),  (float)((double)KSC * 3.43273939e-07),
  (float)((double)KSC * -3.5233877e-06),  (float)((double)KSC * -4.39150654e-06),
  (float)((double)KSC * 0.00021858087),   (float)((double)KSC * -0.00125372503),
  (float)((double)KSC * -0.00417768164),  (float)((double)KSC * 0.246640727),
  (float)((double)KSC * 1.50140941)};
__device__ __constant__ const float CT[9] = {  // tail, w>=5, s = sqrt(w)-3
  (float)((double)KSC * -0.000200214257), (float)((double)KSC * 0.000100950558),
  (float)((double)KSC * 0.00134934322),   (float)((double)KSC * -0.00367342844),
  (float)((double)KSC * 0.00573950773),   (float)((double)KSC * -0.0076224613),
  (float)((double)KSC * 0.00943887047),   (float)((double)KSC * 1.00167406),
  (float)((double)KSC * 2.83297682)};

// Branchless noise: bits -> uniform -> 0.1*sqrt2*erfinv, deterministic cost.
__device__ __forceinline__ float noise_from_bits(uint32_t b) {
#pragma clang fp contract(off)
  float f = __uint_as_float((b >> 9) | 0x3f800000u) - 1.0f;
  float u = fmaf(f, 2.0f, -0.99999994f);
  float t = u * u;          // ref-identical two roundings — do NOT fma
  float v = 1.0f - t;       // v in [1.19e-7, 1]
  float g = __builtin_amdgcn_logf(v);            // log2(v) <= 0, raw v_log_f32
  float w = -0.69314718f * g;                    // ln(1/v), [0, ~15.95]
  bool  c = w < 5.0f;
  float sc = fmaf(-0.69314718f, g, -2.5f);       // w - 2.5 (single rounding)
  float st = __builtin_amdgcn_sqrtf(w) - 3.0f;   // raw sqrt, 1 ulp — in budget
  float s  = c ? sc : st;
  float p  =          (c ? CC[0] : CT[0]);
  p = fmaf(p, s, c ? CC[1] : CT[1]);
  p = fmaf(p, s, c ? CC[2] : CT[2]);
  p = fmaf(p, s, c ? CC[3] : CT[3]);
  p = fmaf(p, s, c ? CC[4] : CT[4]);
  p = fmaf(p, s, c ? CC[5] : CT[5]);
  p = fmaf(p, s, c ? CC[6] : CT[6]);
  p = fmaf(p, s, c ? CC[7] : CT[7]);
  p = fmaf(p, s, c ? CC[8] : CT[8]);
  return p * u;  // scale already folded into coefficients
}

__device__ __forceinline__ float clamp01(float v) {
  return __builtin_amdgcn_fmed3f(v, 0.0f, 1.0f);
}

__global__ __launch_bounds__(256) void diffusion_kernel(
    const float* __restrict__ x, float* __restrict__ out) {
  // Step keys (partitionable split): key_t = threefry((0,1), (0,t)).
  __shared__ alignas(16) uint2 skeys[TS + 1];
  const int tid = threadIdx.x;
  for (int j = tid; j < TS + 1; j += 256) {
    uint32_t o0, o1;
    tf2x32(0u, 1u, 0u, (uint32_t)(j < TS ? j : 0), o0, o1);
    skeys[j] = make_uint2(o0, o1);
  }
  __syncthreads();

  const uint32_t i = blockIdx.x * 256u + (uint32_t)tid;  // exact grid
  const uint32_t base = i * EPT;

  float4 xv = ((const float4*)x)[i];
  float v[EPT] = {xv.x, xv.y, xv.z, xv.w};

  uint2 kcur = skeys[0];
  for (int t = 0; t < TS; ++t) {
    const uint32_t k0 = (uint32_t)__builtin_amdgcn_readfirstlane((int)kcur.x);
    const uint32_t k1 = (uint32_t)__builtin_amdgcn_readfirstlane((int)kcur.y);
    kcur = skeys[t + 1];  // prefetch next key
    uint32_t b[EPT];
#pragma unroll
    for (uint32_t e = 0; e < EPT; ++e) b[e] = tf_bits(k0, k1, base + e);
#pragma unroll
    for (uint32_t e = 0; e < EPT; ++e) {
      v[e] = clamp01(v[e] + noise_from_bits(b[e]));
    }
  }

  // rev_key = fold_in(key(2), 999) = threefry((0,2),(0,999)) — constant-folded.
  uint32_t rk0, rk1;
  tf2x32(0u, 2u, 0u, 999u, rk0, rk1);
  float4 ov;
  float* op = &ov.x;
#pragma unroll
  for (uint32_t e = 0; e < EPT; ++e) {
    float r = noise_from_bits(tf_bits(rk0, rk1, base + e));
    op[e] = clamp01(v[e] - r);
  }
  ((float4*)out)[i] = ov;
}

extern "C" void kernel_launch(void* const* d_in, const int* in_sizes, int n_in,
                              void* d_out, int out_size, void* d_ws, size_t ws_size,
                              hipStream_t stream) {
  (void)in_sizes; (void)n_in; (void)d_ws; (void)ws_size; (void)out_size;
  const float* x = (const float*)d_in[0];
  float* out = (float*)d_out;
  dim3 block(256);
  dim3 grid(NTHREADS / 256);  // 24576 blocks
  hipLaunchKernelGGL(diffusion_kernel, grid, block, 0, stream, x, out);
}